// Round 1
// baseline (7567.210 us; speedup 1.0000x reference)
//
#include <hip/hip_runtime.h>
#include <hip/hip_fp16.h>

#define LOG2PI_F 1.8378770664093453f

// ---------------- f16 dot2 helper ----------------
typedef _Float16 hf2_t __attribute__((ext_vector_type(2)));

#if defined(__has_builtin)
#  if __has_builtin(__builtin_amdgcn_fdot2)
#    define USE_FDOT2 1
#  endif
#endif
#ifndef USE_FDOT2
#  define USE_FDOT2 0
#endif

__device__ __forceinline__ float fdot2(unsigned int a, unsigned int b, float c) {
#if USE_FDOT2
  return __builtin_amdgcn_fdot2(__builtin_bit_cast(hf2_t, a),
                                __builtin_bit_cast(hf2_t, b), c, false);
#else
  __half2 ha = __builtin_bit_cast(__half2, a);
  __half2 hb = __builtin_bit_cast(__half2, b);
  float2 fa = __half22float2(ha);
  float2 fb = __half22float2(hb);
  return c + fa.x * fb.x + fa.y * fb.y;
#endif
}

__device__ __forceinline__ unsigned int packh2(float lo, float hi) {
  unsigned int l = (unsigned int)__half_as_ushort(__float2half(lo));
  unsigned int h = (unsigned int)__half_as_ushort(__float2half(hi));
  return (h << 16) | l;
}

__device__ __forceinline__ float sigmoid_f(float x) { return 1.f / (1.f + __expf(-x)); }
__device__ __forceinline__ float silu_f(float x) { return x * sigmoid_f(x); }
__device__ __forceinline__ float softplus_f(float x) {
  return fmaxf(x, 0.f) + log1pf(__expf(-fabsf(x)));
}
__device__ __forceinline__ float tanh_f(float x) {
  float ax = fabsf(x);
  float e = __expf(2.f * ax);
  return copysignf(1.f - 2.f / (e + 1.f), x);
}

// ---------------- prep kernels ----------------
__global__ void transpose_k(const float* __restrict__ in, float* __restrict__ out,
                            int R, int C) {
  int i = blockIdx.x * 256 + threadIdx.x;
  if (i < R * C) {
    int r = i / C, c = i % C;
    out[c * R + r] = in[i];
  }
}

// W_hh [768,256] fp32 -> WpkT [128][768] u32 (packed f16 pair per dword, transposed)
__global__ void whh_pack(const float* __restrict__ W, unsigned int* __restrict__ WpkT) {
  int i = blockIdx.x * 256 + threadIdx.x;  // 0..98303, i = d*768+g
  if (i < 98304) {
    int d = i / 768, g = i % 768;
    float lo = W[g * 256 + 2 * d];
    float hi = W[g * 256 + 2 * d + 1];
    WpkT[i] = packh2(lo, hi);
  }
}

// ---------------- gi = x @ W_ih^T + b_ih ----------------
// one block per (b,t) row; WT layout [64][768]
__global__ void gi_gemm(const float* __restrict__ x, const float* __restrict__ WT,
                        const float* __restrict__ bih, float* __restrict__ gi) {
  int m = blockIdx.x;
  int g = threadIdx.x;
  const float* xr = x + m * 64;
  float a0 = bih[g], a1 = bih[g + 256], a2 = bih[g + 512];
#pragma unroll
  for (int k = 0; k < 64; k++) {
    float xv = xr[k];
    const float* w = WT + k * 768;
    a0 = fmaf(w[g], xv, a0);
    a1 = fmaf(w[g + 256], xv, a1);
    a2 = fmaf(w[g + 512], xv, a2);
  }
  float* o = gi + m * 768;
  o[g] = a0;
  o[g + 256] = a1;
  o[g + 512] = a2;
}

// ---------------- GRU scan: one block per batch, weights in registers ----------------
__global__ __launch_bounds__(256, 1) void gru_kernel(
    const unsigned int* __restrict__ WpkT,  // [128][768]
    const float* __restrict__ gi,           // [8,2048,768]
    const float* __restrict__ bhh,          // [768]
    float* __restrict__ h_seq)              // [8,2048,256]
{
  const int b = blockIdx.x;
  const int j = threadIdx.x;  // 0..255, owns h-dim j (rows j, j+256, j+512)

  uint4 w0[32], w1[32], w2[32];
#pragma unroll
  for (int i = 0; i < 32; i++) {
    int d = 4 * i;
    w0[i] = make_uint4(WpkT[(d + 0) * 768 + j], WpkT[(d + 1) * 768 + j],
                       WpkT[(d + 2) * 768 + j], WpkT[(d + 3) * 768 + j]);
    w1[i] = make_uint4(WpkT[(d + 0) * 768 + j + 256], WpkT[(d + 1) * 768 + j + 256],
                       WpkT[(d + 2) * 768 + j + 256], WpkT[(d + 3) * 768 + j + 256]);
    w2[i] = make_uint4(WpkT[(d + 0) * 768 + j + 512], WpkT[(d + 1) * 768 + j + 512],
                       WpkT[(d + 2) * 768 + j + 512], WpkT[(d + 3) * 768 + j + 512]);
  }

  __shared__ __align__(16) unsigned int hpk[2][128];
  if (j < 128) hpk[0][j] = 0u;

  const float br = bhh[j], bz = bhh[j + 256], bn = bhh[j + 512];
  float h = 0.f;
  const float* gib = gi + b * 2048 * 768;
  float* hsb = h_seq + b * 2048 * 256;
  __syncthreads();

  for (int t = 0; t < 2048; t++) {
    const float* g3 = gib + t * 768;
    float gr = g3[j];
    float gz = g3[j + 256];
    float gn = g3[j + 512];

    const uint4* hp = (const uint4*)hpk[t & 1];
    float a0 = br, a1 = bz, a2 = bn;
#pragma unroll
    for (int i = 0; i < 32; i++) {
      uint4 hv = hp[i];
      a0 = fdot2(w0[i].x, hv.x, a0);
      a0 = fdot2(w0[i].y, hv.y, a0);
      a0 = fdot2(w0[i].z, hv.z, a0);
      a0 = fdot2(w0[i].w, hv.w, a0);
      a1 = fdot2(w1[i].x, hv.x, a1);
      a1 = fdot2(w1[i].y, hv.y, a1);
      a1 = fdot2(w1[i].z, hv.z, a1);
      a1 = fdot2(w1[i].w, hv.w, a1);
      a2 = fdot2(w2[i].x, hv.x, a2);
      a2 = fdot2(w2[i].y, hv.y, a2);
      a2 = fdot2(w2[i].z, hv.z, a2);
      a2 = fdot2(w2[i].w, hv.w, a2);
    }

    float rv = sigmoid_f(gr + a0);
    float zv = sigmoid_f(gz + a1);
    float nv = tanh_f(gn + rv * a2);
    float hn = (1.f - zv) * nv + zv * h;
    h = hn;
    hsb[t * 256 + j] = hn;

    float other = __shfl_xor(hn, 1);
    if ((j & 1) == 0) hpk[(t + 1) & 1][j >> 1] = packh2(hn, other);
    __syncthreads();
  }
}

// ---------------- banded softmax attention + ctx = h_global + attn ----------------
#define AW 80
__global__ void attn_kernel(const float* __restrict__ h_seq, const float* __restrict__ t,
                            float* __restrict__ ctx) {
  const int blk = blockIdx.x;
  const int b = blk >> 7;
  const int k0 = (blk & 127) << 4;  // 16 query rows per block
  const int tid = threadIdx.x;

  __shared__ __align__(16) float ewT[176][16];
  __shared__ float ts[176];
  __shared__ float tks[16];
  __shared__ float rden[16];

  const float* tb = t + b * 2048;
  if (tid < 176) {
    int j = k0 - AW + tid;
    ts[tid] = tb[min(max(j, 0), 2047)];
  }
  if (tid < 16) tks[tid] = tb[k0 + tid];
  __syncthreads();

  for (int p = tid; p < 176 * 16; p += 256) {
    int kk = p & 15, jr = p >> 4;
    int j = k0 - AW + jr;
    float d = 2048.f * (tks[kk] - ts[jr]);
    float e = (j >= 0 && j < 2048) ? __expf(-d * d) : 0.f;
    ewT[jr][kk] = e;
  }
  __syncthreads();

  if (tid < 16) {
    float s = 0.f;
    for (int jr = 0; jr < 176; jr++) s += ewT[jr][tid];
    rden[tid] = 1.f / s;  // diagonal term guarantees s >= 1
  }
  __syncthreads();

  float acc[16];
#pragma unroll
  for (int kk = 0; kk < 16; kk++) acc[kk] = 0.f;

  const float* hb = h_seq + b * 2048 * 256;
  for (int jr = 0; jr < 176; jr++) {
    int j = min(max(k0 - AW + jr, 0), 2047);
    float hv = hb[j * 256 + tid];
    const float4* e4 = (const float4*)ewT[jr];
    float4 e0 = e4[0], e1 = e4[1], e2 = e4[2], e3 = e4[3];
    acc[0] = fmaf(e0.x, hv, acc[0]);   acc[1] = fmaf(e0.y, hv, acc[1]);
    acc[2] = fmaf(e0.z, hv, acc[2]);   acc[3] = fmaf(e0.w, hv, acc[3]);
    acc[4] = fmaf(e1.x, hv, acc[4]);   acc[5] = fmaf(e1.y, hv, acc[5]);
    acc[6] = fmaf(e1.z, hv, acc[6]);   acc[7] = fmaf(e1.w, hv, acc[7]);
    acc[8] = fmaf(e2.x, hv, acc[8]);   acc[9] = fmaf(e2.y, hv, acc[9]);
    acc[10] = fmaf(e2.z, hv, acc[10]); acc[11] = fmaf(e2.w, hv, acc[11]);
    acc[12] = fmaf(e3.x, hv, acc[12]); acc[13] = fmaf(e3.y, hv, acc[13]);
    acc[14] = fmaf(e3.z, hv, acc[14]); acc[15] = fmaf(e3.w, hv, acc[15]);
  }

  float hg = hb[2047 * 256 + tid];
  float* cb = ctx + (b * 2048 + k0) * 256 + tid;
#pragma unroll
  for (int kk = 0; kk < 16; kk++) cb[kk * 256] = hg + acc[kk] * rden[kk];
}

// ---------------- init head: m0, s0, log_q0 ----------------
__global__ void init_head(const float* __restrict__ ctx, const float* __restrict__ WT1,
                          const float* __restrict__ bi1, const float* __restrict__ WT2,
                          const float* __restrict__ bi2, const float* __restrict__ eps0,
                          float* __restrict__ m0s0, float* __restrict__ lq0) {
  int b = blockIdx.x;
  int g = threadIdx.x;
  __shared__ float xs[256], his[256], ms[64], red[32];
  xs[g] = ctx[(b * 2048) * 256 + g];  // h0_ctx = h_global + attn[:,0,:]
  __syncthreads();
  float acc = bi1[g];
#pragma unroll 8
  for (int k = 0; k < 256; k++) acc = fmaf(WT1[k * 256 + g], xs[k], acc);
  his[g] = silu_f(acc);
  __syncthreads();
  if (g < 64) {
    float a2 = bi2[g];
#pragma unroll 8
    for (int k = 0; k < 256; k++) a2 = fmaf(WT2[k * 64 + g], his[k], a2);
    float v = (g < 32) ? a2 : (softplus_f(a2) + 1e-6f);
    m0s0[b * 64 + g] = v;
    ms[g] = v;
  }
  __syncthreads();
  if (g < 32) {
    float m = ms[g], s = ms[32 + g];
    float c0 = m + s * eps0[b * 32 + g];
    float sc = fmaxf(s, 1e-12f);
    float z = (c0 - m) / sc;
    red[g] = z * z + 2.f * __logf(sc) + LOG2PI_F;
  }
  __syncthreads();
  if (g == 0) {
    float s = 0.f;
    for (int i = 0; i < 32; i++) s += red[i];
    lq0[b] = -0.5f * s;
  }
}

// ---------------- step-head dense layer (M-tile=4) ----------------
// C[m][g] = act( sum_k A[m][k]*WT[k][g] + bias[g] (+ tvec[m]*wext[g]) )
__global__ void head_layer(const float* __restrict__ A, const float* __restrict__ WT,
                           const float* __restrict__ bias, const float* __restrict__ wext,
                           const float* __restrict__ tvec, float* __restrict__ C,
                           int N, int act) {
  int m0 = blockIdx.x * 4;
  int g = threadIdx.x;
  __shared__ __align__(16) float As[4][256];
#pragma unroll
  for (int r = 0; r < 4; r++) As[r][g] = A[(m0 + r) * 256 + g];
  __syncthreads();
  if (g < N) {
    float b0 = bias[g];
    float acc[4] = {b0, b0, b0, b0};
    for (int k4 = 0; k4 < 64; k4++) {
      const float* w = WT + (k4 * 4) * N + g;
      float w0v = w[0], w1v = w[N], w2v = w[2 * N], w3v = w[3 * N];
#pragma unroll
      for (int r = 0; r < 4; r++) {
        float4 xv = *(const float4*)(&As[r][k4 * 4]);
        acc[r] = fmaf(w0v, xv.x, acc[r]);
        acc[r] = fmaf(w1v, xv.y, acc[r]);
        acc[r] = fmaf(w2v, xv.z, acc[r]);
        acc[r] = fmaf(w3v, xv.w, acc[r]);
      }
    }
#pragma unroll
    for (int r = 0; r < 4; r++) {
      float a = acc[r];
      if (wext) a = fmaf(tvec[m0 + r], wext[g], a);
      if (act) a = silu_f(a);
      C[(m0 + r) * N + g] = a;
    }
  }
}

// ---------------- OU posterior scan + log_q ----------------
__global__ void ou_kernel(const float* __restrict__ params, const float* __restrict__ t,
                          const float* __restrict__ eps, const float* __restrict__ eps0,
                          const float* __restrict__ m0s0, const float* __restrict__ lq0,
                          float* __restrict__ out) {
  int b = blockIdx.x * 2 + (threadIdx.x >> 5);
  int c = threadIdx.x & 31;
  float m0 = m0s0[b * 64 + c];
  float s0 = m0s0[b * 64 + 32 + c];
  float cc = m0 + s0 * eps0[b * 32 + c];
  out[(b * 2048) * 32 + c] = cc;

  float lq = 0.f;
  const float* tb = t + b * 2048;
  for (int k = 0; k < 2047; k++) {
    const float* pr = params + (b * 2048 + k) * 96;
    float mu = pr[c];
    float kap = softplus_f(pr[32 + c]) + 1e-6f;
    float sg = softplus_f(pr[64 + c]) + 1e-6f;
    float dt = fmaxf(tb[k + 1] - tb[k], 1e-6f);
    float A = __expf(-kap * dt);
    float tkd = 2.f * kap * dt;
    float Qe = sg * sg * (1.f - A * A) / fmaxf(2.f * kap, 1e-12f);
    float kd = kap * dt;
    float Qt = sg * sg * dt * (1.f - kd + tkd * tkd * (1.f / 6.f));
    float Q = (tkd < 1e-6f) ? Qt : Qe;
    float var = fmaxf(Q, 1e-12f);
    float noise = eps[(b * 2047 + k) * 32 + c] * sqrtf(var);
    float mean = mu + A * (cc - mu);
    cc = mean + noise;
    out[(b * 2048 + k + 1) * 32 + c] = cc;
    lq += noise * noise / var + __logf(var) + LOG2PI_F;
  }
  lq *= -0.5f;
  for (int off = 16; off >= 1; off >>= 1) lq += __shfl_down(lq, off, 32);
  if (c == 0) out[8 * 2048 * 32 + b] = lq + lq0[b];
}

// ---------------- launcher ----------------
extern "C" void kernel_launch(void* const* d_in, const int* in_sizes, int n_in,
                              void* d_out, int out_size, void* d_ws, size_t ws_size,
                              hipStream_t stream) {
  (void)in_sizes; (void)n_in; (void)out_size; (void)ws_size;
  const float* x    = (const float*)d_in[0];
  const float* t    = (const float*)d_in[1];
  const float* eps0 = (const float*)d_in[2];
  const float* eps  = (const float*)d_in[3];
  const float* W_ih = (const float*)d_in[4];
  const float* W_hh = (const float*)d_in[5];
  const float* b_ih = (const float*)d_in[6];
  const float* b_hh = (const float*)d_in[7];
  const float* Wi1  = (const float*)d_in[8];
  const float* bi1  = (const float*)d_in[9];
  const float* Wi2  = (const float*)d_in[10];
  const float* bi2  = (const float*)d_in[11];
  const float* Ws1  = (const float*)d_in[12];
  const float* bs1  = (const float*)d_in[13];
  const float* Ws2  = (const float*)d_in[14];
  const float* bs2  = (const float*)d_in[15];
  const float* Ws3  = (const float*)d_in[16];
  const float* bs3  = (const float*)d_in[17];
  float* out = (float*)d_out;
  float* ws = (float*)d_ws;

  // workspace layout (float offsets)
  float*        WT_ih = ws + 0;                        // 64x768   = 49152
  unsigned int* WpkT  = (unsigned int*)(ws + 49152);   // 128x768  = 98304
  float*        WT1   = ws + 147456;                   // 256x256  = 65536
  float*        WT2   = ws + 212992;                   // 256x64   = 16384
  float*        WTs1  = ws + 229376;                   // 257x256  = 65792
  float*        WTs2  = ws + 295168;                   // 256x256  = 65536
  float*        WTs3  = ws + 360704;                   // 256x96   = 24576
  float*        m0s0  = ws + 385280;                   // 8x64
  float*        lq0   = ws + 385792;                   // 8
  float*        gi    = ws + 385800;                   // 8x2048x768 = 12582912
  float*        h_seq = gi + 12582912;                 // 8x2048x256 = 4194304
  float*        ctx   = h_seq + 4194304;               // 8x2048x256 = 4194304
  // reuse gi region after GRU:
  float*        hs1    = gi;                           // 4194304
  float*        hs2    = gi + 4194304;                 // 4194304
  float*        params = gi + 8388608;                 // 8x2048x96 = 1572864

  // prep
  transpose_k<<<(768 * 64 + 255) / 256, 256, 0, stream>>>(W_ih, WT_ih, 768, 64);
  transpose_k<<<(256 * 256 + 255) / 256, 256, 0, stream>>>(Wi1, WT1, 256, 256);
  transpose_k<<<(64 * 256 + 255) / 256, 256, 0, stream>>>(Wi2, WT2, 64, 256);
  transpose_k<<<(256 * 257 + 255) / 256, 256, 0, stream>>>(Ws1, WTs1, 256, 257);
  transpose_k<<<(256 * 256 + 255) / 256, 256, 0, stream>>>(Ws2, WTs2, 256, 256);
  transpose_k<<<(96 * 256 + 255) / 256, 256, 0, stream>>>(Ws3, WTs3, 96, 256);
  whh_pack<<<384, 256, 0, stream>>>(W_hh, WpkT);

  // pipeline
  gi_gemm<<<16384, 256, 0, stream>>>(x, WT_ih, b_ih, gi);
  gru_kernel<<<8, 256, 0, stream>>>(WpkT, gi, b_hh, h_seq);
  attn_kernel<<<1024, 256, 0, stream>>>(h_seq, t, ctx);
  init_head<<<8, 256, 0, stream>>>(ctx, WT1, bi1, WT2, bi2, eps0, m0s0, lq0);
  head_layer<<<4096, 256, 0, stream>>>(ctx, WTs1, bs1, WTs1 + 256 * 256, t, hs1, 256, 1);
  head_layer<<<4096, 256, 0, stream>>>(hs1, WTs2, bs2, nullptr, nullptr, hs2, 256, 1);
  head_layer<<<4096, 256, 0, stream>>>(hs2, WTs3, bs3, nullptr, nullptr, params, 96, 0);
  ou_kernel<<<4, 64, 0, stream>>>(params, t, eps, eps0, m0s0, lq0, out);
}

// Round 2
// 3155.955 us; speedup vs baseline: 2.3978x; 2.3978x over previous
//
#include <hip/hip_runtime.h>
#include <hip/hip_fp16.h>

#define LOG2PI_F 1.8378770664093453f

// ---------------- f16 dot2 helper ----------------
typedef _Float16 hf2_t __attribute__((ext_vector_type(2)));

#if defined(__has_builtin)
#  if __has_builtin(__builtin_amdgcn_fdot2)
#    define USE_FDOT2 1
#  endif
#endif
#ifndef USE_FDOT2
#  define USE_FDOT2 0
#endif

__device__ __forceinline__ float fdot2(unsigned int a, unsigned int b, float c) {
#if USE_FDOT2
  return __builtin_amdgcn_fdot2(__builtin_bit_cast(hf2_t, a),
                                __builtin_bit_cast(hf2_t, b), c, false);
#else
  __half2 ha = __builtin_bit_cast(__half2, a);
  __half2 hb = __builtin_bit_cast(__half2, b);
  float2 fa = __half22float2(ha);
  float2 fb = __half22float2(hb);
  return c + fa.x * fb.x + fa.y * fb.y;
#endif
}

__device__ __forceinline__ unsigned int packh2(float lo, float hi) {
  unsigned int l = (unsigned int)__half_as_ushort(__float2half(lo));
  unsigned int h = (unsigned int)__half_as_ushort(__float2half(hi));
  return (h << 16) | l;
}

__device__ __forceinline__ float sigmoid_f(float x) { return 1.f / (1.f + __expf(-x)); }
__device__ __forceinline__ float silu_f(float x) { return x * sigmoid_f(x); }
__device__ __forceinline__ float softplus_f(float x) {
  return fmaxf(x, 0.f) + log1pf(__expf(-fabsf(x)));
}
__device__ __forceinline__ float tanh_f(float x) {
  float ax = fabsf(x);
  float e = __expf(2.f * ax);
  return copysignf(1.f - 2.f / (e + 1.f), x);
}

// ---------------- prep kernels ----------------
__global__ void transpose_k(const float* __restrict__ in, float* __restrict__ out,
                            int R, int C) {
  int i = blockIdx.x * 256 + threadIdx.x;
  if (i < R * C) {
    int r = i / C, c = i % C;
    out[c * R + r] = in[i];
  }
}

// W_hh [768,256] fp32 -> WpkT [128][768] u32 (packed f16 pair per dword, d-major)
__global__ void whh_pack(const float* __restrict__ W, unsigned int* __restrict__ WpkT) {
  int i = blockIdx.x * 256 + threadIdx.x;  // i = d*768+g
  if (i < 98304) {
    int d = i / 768, g = i % 768;
    float lo = W[g * 256 + 2 * d];
    float hi = W[g * 256 + 2 * d + 1];
    WpkT[i] = packh2(lo, hi);
  }
}

// ---------------- gi = x @ W_ih^T + b_ih (M-tile 8) ----------------
__global__ void gi_gemm(const float* __restrict__ x, const float* __restrict__ WT,
                        const float* __restrict__ bih, float* __restrict__ gi) {
  int m0 = blockIdx.x * 8;
  int g = threadIdx.x;
  __shared__ float xs[8][64];
  for (int i = g; i < 512; i += 256) xs[i >> 6][i & 63] = x[m0 * 64 + i];
  __syncthreads();
  float b0 = bih[g], b1 = bih[g + 256], b2 = bih[g + 512];
  float a0[8], a1[8], a2[8];
#pragma unroll
  for (int r = 0; r < 8; r++) { a0[r] = b0; a1[r] = b1; a2[r] = b2; }
  for (int k = 0; k < 64; k++) {
    const float* w = WT + k * 768;
    float w0 = w[g], w1 = w[g + 256], w2 = w[g + 512];
#pragma unroll
    for (int r = 0; r < 8; r++) {
      float xv = xs[r][k];
      a0[r] = fmaf(w0, xv, a0[r]);
      a1[r] = fmaf(w1, xv, a1[r]);
      a2[r] = fmaf(w2, xv, a2[r]);
    }
  }
#pragma unroll
  for (int r = 0; r < 8; r++) {
    float* o = gi + (m0 + r) * 768;
    o[g] = a0[r];
    o[g + 256] = a1[r];
    o[g + 512] = a2[r];
  }
}

// ---------------- GRU scan: one block/batch, 768 threads = 1 thread per gate-row ----
// Weights: 128 packed-f16 dwords per thread -> fits addressable VGPRs, no spill.
__global__ __launch_bounds__(768, 3) void gru_kernel(
    const unsigned int* __restrict__ WpkT,  // [128][768]
    const float* __restrict__ gi,           // [8,2048,768]
    const float* __restrict__ bhh,          // [768]
    float* __restrict__ h_seq)              // [8,2048,256]
{
  const int b = blockIdx.x;
  const int g = threadIdx.x;  // gate-row 0..767

  uint4 w[32];
#pragma unroll
  for (int i = 0; i < 32; i++) {
    int d = 4 * i;
    w[i] = make_uint4(WpkT[(d + 0) * 768 + g], WpkT[(d + 1) * 768 + g],
                      WpkT[(d + 2) * 768 + g], WpkT[(d + 3) * 768 + g]);
  }

  __shared__ __align__(16) unsigned int hpk[2][128];
  __shared__ float als[1024];
  if (g < 128) hpk[0][g] = 0u;

  const float bb = bhh[g];
  float h = 0.f;  // h-state for dim g (valid for g<256)
  const float* gib = gi + b * 2048 * 768;
  float* hsb = h_seq + b * 2048 * 256;
  float gcur = gib[g];
  __syncthreads();

  for (int t = 0; t < 2048; t++) {
    float gnext = gib[min(t + 1, 2047) * 768 + g];  // prefetch next step's gi

    const uint4* hp = (const uint4*)hpk[t & 1];
    float a = bb;
#pragma unroll
    for (int i = 0; i < 32; i++) {
      uint4 hv = hp[i];
      a = fdot2(w[i].x, hv.x, a);
      a = fdot2(w[i].y, hv.y, a);
      a = fdot2(w[i].z, hv.z, a);
      a = fdot2(w[i].w, hv.w, a);
    }
    // als[0:512)  = i_r+h_r, i_z+h_z ; als[512:768) = h_n ; als[768:1024) = i_n
    if (g < 512) {
      als[g] = a + gcur;
    } else {
      als[g] = a;
      als[g + 256] = gcur;
    }
    __syncthreads();

    if (g < 256) {
      float rv = sigmoid_f(als[g]);
      float zv = sigmoid_f(als[256 + g]);
      float nv = tanh_f(als[768 + g] + rv * als[512 + g]);
      float hn = (1.f - zv) * nv + zv * h;
      h = hn;
      hsb[t * 256 + g] = hn;
      float other = __shfl_xor(hn, 1);
      if ((g & 1) == 0) hpk[(t + 1) & 1][g >> 1] = packh2(hn, other);
    }
    gcur = gnext;
    __syncthreads();
  }
}

// ---------------- banded softmax attention + ctx = h_global + attn ----------------
#define AW 80
__global__ void attn_kernel(const float* __restrict__ h_seq, const float* __restrict__ t,
                            float* __restrict__ ctx) {
  const int blk = blockIdx.x;
  const int b = blk >> 7;
  const int k0 = (blk & 127) << 4;  // 16 query rows per block
  const int tid = threadIdx.x;

  __shared__ __align__(16) float ewT[176][16];
  __shared__ float ts[176];
  __shared__ float tks[16];
  __shared__ float rden[16];

  const float* tb = t + b * 2048;
  if (tid < 176) {
    int j = k0 - AW + tid;
    ts[tid] = tb[min(max(j, 0), 2047)];
  }
  if (tid < 16) tks[tid] = tb[k0 + tid];
  __syncthreads();

  for (int p = tid; p < 176 * 16; p += 256) {
    int kk = p & 15, jr = p >> 4;
    int j = k0 - AW + jr;
    float d = 2048.f * (tks[kk] - ts[jr]);
    float e = (j >= 0 && j < 2048) ? __expf(-d * d) : 0.f;
    ewT[jr][kk] = e;
  }
  __syncthreads();

  if (tid < 16) {
    float s = 0.f;
    for (int jr = 0; jr < 176; jr++) s += ewT[jr][tid];
    rden[tid] = 1.f / s;
  }
  __syncthreads();

  float acc[16];
#pragma unroll
  for (int kk = 0; kk < 16; kk++) acc[kk] = 0.f;

  const float* hb = h_seq + b * 2048 * 256;
  for (int jr = 0; jr < 176; jr++) {
    int j = min(max(k0 - AW + jr, 0), 2047);
    float hv = hb[j * 256 + tid];
    const float4* e4 = (const float4*)ewT[jr];
    float4 e0 = e4[0], e1 = e4[1], e2 = e4[2], e3 = e4[3];
    acc[0] = fmaf(e0.x, hv, acc[0]);   acc[1] = fmaf(e0.y, hv, acc[1]);
    acc[2] = fmaf(e0.z, hv, acc[2]);   acc[3] = fmaf(e0.w, hv, acc[3]);
    acc[4] = fmaf(e1.x, hv, acc[4]);   acc[5] = fmaf(e1.y, hv, acc[5]);
    acc[6] = fmaf(e1.z, hv, acc[6]);   acc[7] = fmaf(e1.w, hv, acc[7]);
    acc[8] = fmaf(e2.x, hv, acc[8]);   acc[9] = fmaf(e2.y, hv, acc[9]);
    acc[10] = fmaf(e2.z, hv, acc[10]); acc[11] = fmaf(e2.w, hv, acc[11]);
    acc[12] = fmaf(e3.x, hv, acc[12]); acc[13] = fmaf(e3.y, hv, acc[13]);
    acc[14] = fmaf(e3.z, hv, acc[14]); acc[15] = fmaf(e3.w, hv, acc[15]);
  }

  float hg = hb[2047 * 256 + tid];
  float* cb = ctx + (b * 2048 + k0) * 256 + tid;
#pragma unroll
  for (int kk = 0; kk < 16; kk++) cb[kk * 256] = hg + acc[kk] * rden[kk];
}

// ---------------- init head: m0, s0, log_q0 ----------------
__global__ void init_head(const float* __restrict__ ctx, const float* __restrict__ WT1,
                          const float* __restrict__ bi1, const float* __restrict__ WT2,
                          const float* __restrict__ bi2, const float* __restrict__ eps0,
                          float* __restrict__ m0s0, float* __restrict__ lq0) {
  int b = blockIdx.x;
  int g = threadIdx.x;
  __shared__ float xs[256], his[256], ms[64], red[32];
  xs[g] = ctx[(b * 2048) * 256 + g];
  __syncthreads();
  float acc = bi1[g];
#pragma unroll 8
  for (int k = 0; k < 256; k++) acc = fmaf(WT1[k * 256 + g], xs[k], acc);
  his[g] = silu_f(acc);
  __syncthreads();
  if (g < 64) {
    float a2 = bi2[g];
#pragma unroll 8
    for (int k = 0; k < 256; k++) a2 = fmaf(WT2[k * 64 + g], his[k], a2);
    float v = (g < 32) ? a2 : (softplus_f(a2) + 1e-6f);
    m0s0[b * 64 + g] = v;
    ms[g] = v;
  }
  __syncthreads();
  if (g < 32) {
    float m = ms[g], s = ms[32 + g];
    float c0 = m + s * eps0[b * 32 + g];
    float sc = fmaxf(s, 1e-12f);
    float z = (c0 - m) / sc;
    red[g] = z * z + 2.f * __logf(sc) + LOG2PI_F;
  }
  __syncthreads();
  if (g == 0) {
    float s = 0.f;
    for (int i = 0; i < 32; i++) s += red[i];
    lq0[b] = -0.5f * s;
  }
}

// ---------------- step-head dense layer (M-tile=8) ----------------
__global__ void head_layer(const float* __restrict__ A, const float* __restrict__ WT,
                           const float* __restrict__ bias, const float* __restrict__ wext,
                           const float* __restrict__ tvec, float* __restrict__ C,
                           int N, int act) {
  int m0 = blockIdx.x * 8;
  int g = threadIdx.x;
  __shared__ __align__(16) float As[8][256];
#pragma unroll
  for (int r = 0; r < 8; r++) As[r][g] = A[(m0 + r) * 256 + g];
  __syncthreads();
  if (g < N) {
    float b0 = bias[g];
    float acc[8] = {b0, b0, b0, b0, b0, b0, b0, b0};
    for (int k4 = 0; k4 < 64; k4++) {
      const float* w = WT + (k4 * 4) * N + g;
      float w0v = w[0], w1v = w[N], w2v = w[2 * N], w3v = w[3 * N];
#pragma unroll
      for (int r = 0; r < 8; r++) {
        float4 xv = *(const float4*)(&As[r][k4 * 4]);
        acc[r] = fmaf(w0v, xv.x, acc[r]);
        acc[r] = fmaf(w1v, xv.y, acc[r]);
        acc[r] = fmaf(w2v, xv.z, acc[r]);
        acc[r] = fmaf(w3v, xv.w, acc[r]);
      }
    }
#pragma unroll
    for (int r = 0; r < 8; r++) {
      float a = acc[r];
      if (wext) a = fmaf(tvec[m0 + r], wext[g], a);
      if (act) a = silu_f(a);
      C[(m0 + r) * N + g] = a;
    }
  }
}

// ---------------- OU posterior: parallel segmented scan ----------------
// c_{k+1} = A_k c_k + d_k  (d_k = mu(1-A)+eps*sqrt(var)); log_q term = eps^2+log var+LOG2PI
__global__ __launch_bounds__(1024) void ou_kernel(
    const float* __restrict__ params, const float* __restrict__ t,
    const float* __restrict__ eps, const float* __restrict__ eps0,
    const float* __restrict__ m0s0, const float* __restrict__ lq0,
    float* __restrict__ out) {
  const int b = blockIdx.x;
  const int c = threadIdx.x & 31;
  const int s = threadIdx.x >> 5;  // segment 0..31
  const int k0 = s * 64;
  const int k1 = min(k0 + 64, 2047);
  const float* tb = t + b * 2048;

  __shared__ float Ps[32][33], Ss[32][33], Cs[32][33], lqs[32][33];

  // phase 1: per-segment composite (P, S) + independent log_q partial
  float P = 1.f, S = 0.f, lq = 0.f;
  for (int k = k0; k < k1; k++) {
    const float* pr = params + (b * 2048 + k) * 96;
    float mu = pr[c];
    float kap = softplus_f(pr[32 + c]) + 1e-6f;
    float sg = softplus_f(pr[64 + c]) + 1e-6f;
    float dt = fmaxf(tb[k + 1] - tb[k], 1e-6f);
    float A = __expf(-kap * dt);
    float tkd = 2.f * kap * dt;
    float Qe = sg * sg * (1.f - A * A) / fmaxf(2.f * kap, 1e-12f);
    float kd = kap * dt;
    float Qt = sg * sg * dt * (1.f - kd + tkd * tkd * (1.f / 6.f));
    float var = fmaxf((tkd < 1e-6f) ? Qt : Qe, 1e-12f);
    float e = eps[(b * 2047 + k) * 32 + c];
    float d = mu * (1.f - A) + e * sqrtf(var);
    S = fmaf(A, S, d);
    P *= A;
    lq += e * e + __logf(var) + LOG2PI_F;
  }
  Ps[c][s] = P;
  Ss[c][s] = S;
  lqs[c][s] = lq;
  __syncthreads();

  // phase 2: prefix over segments (one thread per chain) + log_q total
  if (s == 0) {
    float m0v = m0s0[b * 64 + c];
    float s0v = m0s0[b * 64 + 32 + c];
    float cc = fmaf(s0v, eps0[b * 32 + c], m0v);
    out[(b * 2048) * 32 + c] = cc;
    float lqt = 0.f;
    for (int i = 0; i < 32; i++) {
      Cs[c][i] = cc;
      cc = fmaf(Ps[c][i], cc, Ss[c][i]);
      lqt += lqs[c][i];
    }
    for (int off = 16; off >= 1; off >>= 1) lqt += __shfl_down(lqt, off, 32);
    if (c == 0) out[8 * 2048 * 32 + b] = lq0[b] - 0.5f * lqt;
  }
  __syncthreads();

  // phase 3: replay segment from its start value, write c
  float cc = Cs[c][s];
  for (int k = k0; k < k1; k++) {
    const float* pr = params + (b * 2048 + k) * 96;
    float mu = pr[c];
    float kap = softplus_f(pr[32 + c]) + 1e-6f;
    float sg = softplus_f(pr[64 + c]) + 1e-6f;
    float dt = fmaxf(tb[k + 1] - tb[k], 1e-6f);
    float A = __expf(-kap * dt);
    float tkd = 2.f * kap * dt;
    float Qe = sg * sg * (1.f - A * A) / fmaxf(2.f * kap, 1e-12f);
    float kd = kap * dt;
    float Qt = sg * sg * dt * (1.f - kd + tkd * tkd * (1.f / 6.f));
    float var = fmaxf((tkd < 1e-6f) ? Qt : Qe, 1e-12f);
    float e = eps[(b * 2047 + k) * 32 + c];
    float d = mu * (1.f - A) + e * sqrtf(var);
    cc = fmaf(A, cc, d);
    out[(b * 2048 + k + 1) * 32 + c] = cc;
  }
}

// ---------------- launcher ----------------
extern "C" void kernel_launch(void* const* d_in, const int* in_sizes, int n_in,
                              void* d_out, int out_size, void* d_ws, size_t ws_size,
                              hipStream_t stream) {
  (void)in_sizes; (void)n_in; (void)out_size; (void)ws_size;
  const float* x    = (const float*)d_in[0];
  const float* t    = (const float*)d_in[1];
  const float* eps0 = (const float*)d_in[2];
  const float* eps  = (const float*)d_in[3];
  const float* W_ih = (const float*)d_in[4];
  const float* W_hh = (const float*)d_in[5];
  const float* b_ih = (const float*)d_in[6];
  const float* b_hh = (const float*)d_in[7];
  const float* Wi1  = (const float*)d_in[8];
  const float* bi1  = (const float*)d_in[9];
  const float* Wi2  = (const float*)d_in[10];
  const float* bi2  = (const float*)d_in[11];
  const float* Ws1  = (const float*)d_in[12];
  const float* bs1  = (const float*)d_in[13];
  const float* Ws2  = (const float*)d_in[14];
  const float* bs2  = (const float*)d_in[15];
  const float* Ws3  = (const float*)d_in[16];
  const float* bs3  = (const float*)d_in[17];
  float* out = (float*)d_out;
  float* ws = (float*)d_ws;

  // workspace layout (float offsets)
  float*        WT_ih = ws + 0;                        // 64x768   = 49152
  unsigned int* WpkT  = (unsigned int*)(ws + 49152);   // 128x768  = 98304
  float*        WT1   = ws + 147456;                   // 256x256  = 65536
  float*        WT2   = ws + 212992;                   // 256x64   = 16384
  float*        WTs1  = ws + 229376;                   // 257x256  = 65792
  float*        WTs2  = ws + 295168;                   // 256x256  = 65536
  float*        WTs3  = ws + 360704;                   // 256x96   = 24576
  float*        m0s0  = ws + 385280;                   // 8x64
  float*        lq0   = ws + 385792;                   // 8
  float*        gi    = ws + 385800;                   // 8x2048x768 = 12582912
  float*        h_seq = gi + 12582912;                 // 8x2048x256 = 4194304
  float*        ctx   = h_seq + 4194304;               // 8x2048x256 = 4194304
  // reuse gi region after GRU:
  float*        hs1    = gi;                           // 4194304
  float*        hs2    = gi + 4194304;                 // 4194304
  float*        params = gi + 8388608;                 // 8x2048x96 = 1572864

  // prep
  transpose_k<<<(768 * 64 + 255) / 256, 256, 0, stream>>>(W_ih, WT_ih, 768, 64);
  transpose_k<<<(256 * 256 + 255) / 256, 256, 0, stream>>>(Wi1, WT1, 256, 256);
  transpose_k<<<(64 * 256 + 255) / 256, 256, 0, stream>>>(Wi2, WT2, 64, 256);
  transpose_k<<<(256 * 257 + 255) / 256, 256, 0, stream>>>(Ws1, WTs1, 256, 257);
  transpose_k<<<(256 * 256 + 255) / 256, 256, 0, stream>>>(Ws2, WTs2, 256, 256);
  transpose_k<<<(96 * 256 + 255) / 256, 256, 0, stream>>>(Ws3, WTs3, 96, 256);
  whh_pack<<<384, 256, 0, stream>>>(W_hh, WpkT);

  // pipeline
  gi_gemm<<<2048, 256, 0, stream>>>(x, WT_ih, b_ih, gi);
  gru_kernel<<<8, 768, 0, stream>>>(WpkT, gi, b_hh, h_seq);
  attn_kernel<<<1024, 256, 0, stream>>>(h_seq, t, ctx);
  init_head<<<8, 256, 0, stream>>>(ctx, WT1, bi1, WT2, bi2, eps0, m0s0, lq0);
  head_layer<<<2048, 256, 0, stream>>>(ctx, WTs1, bs1, WTs1 + 256 * 256, t, hs1, 256, 1);
  head_layer<<<2048, 256, 0, stream>>>(hs1, WTs2, bs2, nullptr, nullptr, hs2, 256, 1);
  head_layer<<<2048, 256, 0, stream>>>(hs2, WTs3, bs3, nullptr, nullptr, params, 96, 0);
  ou_kernel<<<8, 1024, 0, stream>>>(params, t, eps, eps0, m0s0, lq0, out);
}